// Round 1
// baseline (119.876 us; speedup 1.0000x reference)
//
#include <hip/hip_runtime.h>

// LIF multi-step: spikes[t] = Heaviside(h[t] - 1.0), h[t] = 0.5*v + 0.25 + x[t],
// v' = s ? 0.5 : h.  T=64, B=32, N=32768. Memory-bound streaming scan.

#define T_STEPS 64

__global__ __launch_bounds__(256) void lif_kernel(const float4* __restrict__ x,
                                                  float4* __restrict__ out,
                                                  int bn4) {
    int idx = blockIdx.x * blockDim.x + threadIdx.x;
    if (idx >= bn4) return;

    float4 v = make_float4(0.5f, 0.5f, 0.5f, 0.5f);

    #pragma unroll 4
    for (int t = 0; t < T_STEPS; ++t) {
        float4 xt = x[(size_t)t * bn4 + idx];
        float4 s;

        float hx = fmaf(0.5f, v.x, 0.25f + xt.x);
        float hy = fmaf(0.5f, v.y, 0.25f + xt.y);
        float hz = fmaf(0.5f, v.z, 0.25f + xt.z);
        float hw = fmaf(0.5f, v.w, 0.25f + xt.w);

        s.x = (hx >= 1.0f) ? 1.0f : 0.0f;
        s.y = (hy >= 1.0f) ? 1.0f : 0.0f;
        s.z = (hz >= 1.0f) ? 1.0f : 0.0f;
        s.w = (hw >= 1.0f) ? 1.0f : 0.0f;

        v.x = (hx >= 1.0f) ? 0.5f : hx;
        v.y = (hy >= 1.0f) ? 0.5f : hy;
        v.z = (hz >= 1.0f) ? 0.5f : hz;
        v.w = (hw >= 1.0f) ? 0.5f : hw;

        out[(size_t)t * bn4 + idx] = s;
    }
}

extern "C" void kernel_launch(void* const* d_in, const int* in_sizes, int n_in,
                              void* d_out, int out_size, void* d_ws, size_t ws_size,
                              hipStream_t stream) {
    const float4* x = (const float4*)d_in[0];
    float4* out = (float4*)d_out;

    // total elements = T*B*N; per-timestep elements = B*N
    int total = in_sizes[0];
    int bn = total / T_STEPS;
    int bn4 = bn / 4;

    int block = 256;
    int grid = (bn4 + block - 1) / block;
    lif_kernel<<<grid, block, 0, stream>>>(x, out, bn4);
}

// Round 3
// 117.725 us; speedup vs baseline: 1.0183x; 1.0183x over previous
//
#include <hip/hip_runtime.h>

// LIF multi-step: spikes[t] = Heaviside(h[t] - 1.0), h[t] = 0.5*v + 0.25 + x[t],
// v' = s ? 0.5 : h.  T=64, B=32, N=32768. Memory-bound streaming scan.
//
// R2: nontemporal load/store via clang ext_vector_type (HIP_vector_type struct
// is rejected by the builtin), unroll 8, pointer-bump addressing.

#define T_STEPS 64

typedef float f4 __attribute__((ext_vector_type(4)));

__global__ __launch_bounds__(256) void lif_kernel(const f4* __restrict__ x,
                                                  f4* __restrict__ out,
                                                  int bn4) {
    int idx = blockIdx.x * blockDim.x + threadIdx.x;
    if (idx >= bn4) return;

    const f4* __restrict__ xp = x + idx;
    f4* __restrict__ op = out + idx;

    f4 v = {0.5f, 0.5f, 0.5f, 0.5f};

    #pragma unroll 8
    for (int t = 0; t < T_STEPS; ++t) {
        f4 xt = __builtin_nontemporal_load(xp);
        f4 s;

        float hx = fmaf(0.5f, v.x, 0.25f + xt.x);
        float hy = fmaf(0.5f, v.y, 0.25f + xt.y);
        float hz = fmaf(0.5f, v.z, 0.25f + xt.z);
        float hw = fmaf(0.5f, v.w, 0.25f + xt.w);

        s.x = (hx >= 1.0f) ? 1.0f : 0.0f;
        s.y = (hy >= 1.0f) ? 1.0f : 0.0f;
        s.z = (hz >= 1.0f) ? 1.0f : 0.0f;
        s.w = (hw >= 1.0f) ? 1.0f : 0.0f;

        v.x = (hx >= 1.0f) ? 0.5f : hx;
        v.y = (hy >= 1.0f) ? 0.5f : hy;
        v.z = (hz >= 1.0f) ? 0.5f : hz;
        v.w = (hw >= 1.0f) ? 0.5f : hw;

        __builtin_nontemporal_store(s, op);

        xp += bn4;
        op += bn4;
    }
}

extern "C" void kernel_launch(void* const* d_in, const int* in_sizes, int n_in,
                              void* d_out, int out_size, void* d_ws, size_t ws_size,
                              hipStream_t stream) {
    const f4* x = (const f4*)d_in[0];
    f4* out = (f4*)d_out;

    int total = in_sizes[0];
    int bn = total / T_STEPS;
    int bn4 = bn / 4;

    int block = 256;
    int grid = (bn4 + block - 1) / block;
    lif_kernel<<<grid, block, 0, stream>>>(x, out, bn4);
}

// Round 4
// 103.503 us; speedup vs baseline: 1.1582x; 1.1374x over previous
//
#include <hip/hip_runtime.h>

// LIF multi-step: spikes[t] = Heaviside(h[t] - 1.0), h[t] = 0.5*v + 0.25 + x[t],
// v' = s ? 0.5 : h.  T=64, B=32, N=32768. Memory-bound streaming scan.
//
// R3: float2 per thread -> 524288 threads = 32 waves/CU (full occupancy) to
// keep both HBM directions saturated. launch_bounds(256,8) caps VGPR<=64.

#define T_STEPS 64

typedef float f2 __attribute__((ext_vector_type(2)));

__global__ __launch_bounds__(256, 8) void lif_kernel(const f2* __restrict__ x,
                                                     f2* __restrict__ out,
                                                     int bn2) {
    int idx = blockIdx.x * blockDim.x + threadIdx.x;
    if (idx >= bn2) return;

    const f2* __restrict__ xp = x + idx;
    f2* __restrict__ op = out + idx;

    f2 v = {0.5f, 0.5f};

    #pragma unroll 8
    for (int t = 0; t < T_STEPS; ++t) {
        f2 xt = __builtin_nontemporal_load(xp);
        f2 s;

        float hx = fmaf(0.5f, v.x, 0.25f + xt.x);
        float hy = fmaf(0.5f, v.y, 0.25f + xt.y);

        s.x = (hx >= 1.0f) ? 1.0f : 0.0f;
        s.y = (hy >= 1.0f) ? 1.0f : 0.0f;

        v.x = (hx >= 1.0f) ? 0.5f : hx;
        v.y = (hy >= 1.0f) ? 0.5f : hy;

        __builtin_nontemporal_store(s, op);

        xp += bn2;
        op += bn2;
    }
}

extern "C" void kernel_launch(void* const* d_in, const int* in_sizes, int n_in,
                              void* d_out, int out_size, void* d_ws, size_t ws_size,
                              hipStream_t stream) {
    const f2* x = (const f2*)d_in[0];
    f2* out = (f2*)d_out;

    int total = in_sizes[0];
    int bn = total / T_STEPS;
    int bn2 = bn / 2;

    int block = 256;
    int grid = (bn2 + block - 1) / block;
    lif_kernel<<<grid, block, 0, stream>>>(x, out, bn2);
}

// Round 5
// 101.832 us; speedup vs baseline: 1.1772x; 1.0164x over previous
//
#include <hip/hip_runtime.h>

// LIF multi-step: spikes[t] = Heaviside(h[t] - 1.0), h[t] = 0.5*v + 0.25 + x[t],
// v' = s ? 0.5 : h.  T=64, B=32, N=32768. Memory-bound streaming scan.
//
// R4: drop nt from LOADS (let x, exactly 256 MiB = L3 size, be retained in
// Infinity Cache across graph replays); keep nt on STORES (output is
// write-only -> don't let it evict x from L3). f2/thread, 32 waves/CU.

#define T_STEPS 64

typedef float f2 __attribute__((ext_vector_type(2)));

__global__ __launch_bounds__(256, 8) void lif_kernel(const f2* __restrict__ x,
                                                     f2* __restrict__ out,
                                                     int bn2) {
    int idx = blockIdx.x * blockDim.x + threadIdx.x;
    if (idx >= bn2) return;

    const f2* __restrict__ xp = x + idx;
    f2* __restrict__ op = out + idx;

    f2 v = {0.5f, 0.5f};

    #pragma unroll 8
    for (int t = 0; t < T_STEPS; ++t) {
        f2 xt = *xp;   // cacheable: allow L3 retention across replays
        f2 s;

        float hx = fmaf(0.5f, v.x, 0.25f + xt.x);
        float hy = fmaf(0.5f, v.y, 0.25f + xt.y);

        s.x = (hx >= 1.0f) ? 1.0f : 0.0f;
        s.y = (hy >= 1.0f) ? 1.0f : 0.0f;

        v.x = (hx >= 1.0f) ? 0.5f : hx;
        v.y = (hy >= 1.0f) ? 0.5f : hy;

        __builtin_nontemporal_store(s, op);  // write-only stream: no-allocate

        xp += bn2;
        op += bn2;
    }
}

extern "C" void kernel_launch(void* const* d_in, const int* in_sizes, int n_in,
                              void* d_out, int out_size, void* d_ws, size_t ws_size,
                              hipStream_t stream) {
    const f2* x = (const f2*)d_in[0];
    f2* out = (f2*)d_out;

    int total = in_sizes[0];
    int bn = total / T_STEPS;
    int bn2 = bn / 2;

    int block = 256;
    int grid = (bn2 + block - 1) / block;
    lif_kernel<<<grid, block, 0, stream>>>(x, out, bn2);
}